// Round 1
// baseline (61.911 us; speedup 1.0000x reference)
//
#include <hip/hip_runtime.h>

#define HD 1024           // hidden dim D
#define D4 (HD/4)         // float4s per row = 256

// Kernel A: partial column-reduction. Block b handles rows {b, b+G, ...}.
// Thread t owns columns [4t, 4t+4). Writes one float4 partial per (block, t).
__global__ void __launch_bounds__(256) partial_reduce(
        const float* __restrict__ past,   // [N, HD]
        const float* __restrict__ grad,   // [N]
        float* __restrict__ partials,     // [G, HD]
        int N, int G) {
    const int b = blockIdx.x;
    const int t = threadIdx.x;            // 0..255
    const float4* past4 = (const float4*)past;
    float4 acc = make_float4(0.f, 0.f, 0.f, 0.f);
    for (int r = b; r < N; r += G) {
        const float g = grad[r];                       // wave-uniform broadcast
        const float4 v = past4[(size_t)r * D4 + t];    // coalesced 16B/lane
        acc.x += g * v.x;
        acc.y += g * v.y;
        acc.z += g * v.z;
        acc.w += g * v.w;
    }
    ((float4*)partials)[(size_t)b * D4 + t] = acc;
}

// Kernel B: reduce G partial vectors into weighted[HD] via a few atomics.
// Block handles a g-slice; thread t owns columns [4t, 4t+4) (coalesced).
__global__ void __launch_bounds__(256) final_reduce(
        const float* __restrict__ partials,  // [G, HD]
        float* __restrict__ weighted,        // [HD], pre-zeroed
        int G, int per_block) {
    const int t = threadIdx.x;
    const int g0 = blockIdx.x * per_block;
    const float4* p4 = (const float4*)partials;
    float4 acc = make_float4(0.f, 0.f, 0.f, 0.f);
    for (int k = 0; k < per_block; ++k) {
        const int g = g0 + k;
        if (g >= G) break;
        const float4 v = p4[(size_t)g * D4 + t];
        acc.x += v.x; acc.y += v.y; acc.z += v.z; acc.w += v.w;
    }
    atomicAdd(&weighted[4 * t + 0], acc.x);
    atomicAdd(&weighted[4 * t + 1], acc.y);
    atomicAdd(&weighted[4 * t + 2], acc.z);
    atomicAdd(&weighted[4 * t + 3], acc.w);
}

// Kernel C: out[i][j] = weighted[i] * cur[j]. Block = output row i.
__global__ void __launch_bounds__(256) outer_kernel(
        const float* __restrict__ weighted,  // [HD]
        const float* __restrict__ cur,       // [HD]
        float* __restrict__ out) {           // [HD, HD]
    const int i = blockIdx.x;
    const int t = threadIdx.x;
    const float w = weighted[i];                       // wave-uniform
    const float4 c = ((const float4*)cur)[t];          // coalesced
    float4 o;
    o.x = w * c.x; o.y = w * c.y; o.z = w * c.z; o.w = w * c.w;
    ((float4*)out)[(size_t)i * D4 + t] = o;            // coalesced 16B/lane
}

extern "C" void kernel_launch(void* const* d_in, const int* in_sizes, int n_in,
                              void* d_out, int out_size, void* d_ws, size_t ws_size,
                              hipStream_t stream) {
    const float* past = (const float*)d_in[0];   // [N, 1024] fp32
    const float* cur  = (const float*)d_in[1];   // [1024] fp32
    const float* grad = (const float*)d_in[2];   // [N] fp32
    float* out = (float*)d_out;                  // [1024, 1024] fp32
    const int N = in_sizes[2];                   // 65536

    // Workspace layout: weighted[1024] floats, then partials[G][1024] floats.
    float* weighted = (float*)d_ws;
    float* partials = weighted + HD;

    int G = 1024;                                // 4 blocks/CU for BW saturation
    const size_t avail_floats = ws_size / sizeof(float);
    if ((size_t)(HD + (size_t)G * HD) > avail_floats) {
        G = (int)((avail_floats - HD) / HD);
        if (G < 1) G = 1;
    }

    hipMemsetAsync(weighted, 0, HD * sizeof(float), stream);

    partial_reduce<<<G, 256, 0, stream>>>(past, grad, partials, N, G);

    int nb = 64; if (nb > G) nb = G;
    const int per_block = (G + nb - 1) / nb;
    final_reduce<<<nb, 256, 0, stream>>>(partials, weighted, G, per_block);

    outer_kernel<<<HD, 256, 0, stream>>>(weighted, cur, out);
}